// Round 4
// baseline (688.127 us; speedup 1.0000x reference)
//
#include <hip/hip_runtime.h>
#include <hip/hip_fp16.h>
#include <math.h>

#define N_NODES 50000
#define N_EDGES 1200000
#define N_GRAPHS 128
#define D_IN 32
#define D_H 64
#define D_OUT 10
#define ELL_CAP 64

#define EPS 1e-7f
#define MAX_NORM (1.0f - 1e-5f)

// ---------------- wave helpers ----------------

__device__ __forceinline__ float wave_reduce_sum(float v) {
    #pragma unroll
    for (int off = 32; off > 0; off >>= 1)
        v += __shfl_xor(v, off, 64);
    return v;
}

// logmap0(proj(expmap0(u))) on a lane-distributed vector (one component per
// lane; inactive lanes pass 0). Replicates the reference's exact sequence.
__device__ __forceinline__ float exp_proj_log(float m) {
    float n = fmaxf(sqrtf(wave_reduce_sum(m * m)), EPS);
    float v = tanhf(n) * m / n;
    float nv = fmaxf(sqrtf(wave_reduce_sum(v * v)), EPS);
    if (nv > MAX_NORM) v = v * (MAX_NORM / nv);
    float nl = sqrtf(wave_reduce_sum(v * v));
    nl = fminf(fmaxf(nl, EPS), MAX_NORM);
    return atanhf(nl) * v / nl;
}

// ---------------- kernels ----------------

// Build ELL adjacency (ushort src ids): append src[e] to dst[e]'s row.
__global__ void ell_fill_kernel(const int* __restrict__ src, const int* __restrict__ dst,
                                int* __restrict__ deg, ushort* __restrict__ ell, int E) {
    int e = blockIdx.x * 256 + threadIdx.x;
    if (e >= E) return;
    int s = src[e];
    int d = dst[e];
    s = min(max(s, 0), N_NODES - 1);
    d = min(max(d, 0), N_NODES - 1);
    int pos = atomicAdd(&deg[d], 1);
    if (pos < ELL_CAP) ell[d * ELL_CAP + pos] = (ushort)s;
}

// u0 = fp16(logmap0(proj(expmap0(x)))), x: [N, 32]. One wave per node.
__global__ void tangent0_kernel(const float* __restrict__ x, __half* __restrict__ u0, int n) {
    int gid = blockIdx.x * 256 + threadIdx.x;
    int node = gid >> 6;
    int lane = gid & 63;
    if (node >= n) return;
    float m = (lane < D_IN) ? x[node * D_IN + lane] : 0.0f;
    float t = exp_proj_log(m);
    if (lane < D_IN) u0[node * D_IN + lane] = __float2half(t);
}

// Fused HGCN layer: gather-mean over ELL (fp16 source, K dims) -> @W + b
// (exact swap: mean commutes with affine map; deg==0 forced to 0 to match
// segment_mean) -> optional leaky_relu -> expmap0 -> proj -> logmap0 ->
// fp16 store (or atomic pool accumulation for the last layer).
// ONE WAVE PER NODE (TLP hides gather latency — R3 post-mortem); W staged
// in LDS per block (4 waves share), stride-1 LDS reads are conflict-free.
template <int K, int ACT, int POOL>
__global__ void layer_kernel(const __half* __restrict__ uin, const float* __restrict__ W,
                             const float* __restrict__ b, const int* __restrict__ deg,
                             const ushort* __restrict__ ell, __half* __restrict__ uout,
                             const int* __restrict__ batch, float* __restrict__ pooled,
                             float* __restrict__ cntg) {
    __shared__ float Ws[K * 64];
    __shared__ float bs[64];
    int tid = threadIdx.x;
    for (int i = tid; i < K * 64; i += 256) Ws[i] = W[i];
    if (tid < 64) bs[tid] = b[tid];
    __syncthreads();

    int lane = tid & 63;
    int node = blockIdx.x * 4 + (tid >> 6);
    if (node >= N_NODES) return;

    int d_true = deg[node];
    int d = min(d_true, ELL_CAP);
    // one coalesced load: lane e holds neighbor id e
    int id = (lane < d) ? (int)ell[node * ELL_CAP + lane] : 0;
    float acc = 0.0f;
    if (K == 64) {
        int e = 0;
        for (; e + 4 <= d; e += 4) {
            int s0 = __shfl(id, e, 64);
            int s1 = __shfl(id, e + 1, 64);
            int s2 = __shfl(id, e + 2, 64);
            int s3 = __shfl(id, e + 3, 64);
            float v0 = __half2float(uin[s0 * 64 + lane]);
            float v1 = __half2float(uin[s1 * 64 + lane]);
            float v2 = __half2float(uin[s2 * 64 + lane]);
            float v3 = __half2float(uin[s3 * 64 + lane]);
            acc += v0 + v1 + v2 + v3;
        }
        for (; e < d; ++e) {
            int s = __shfl(id, e, 64);
            acc += __half2float(uin[s * 64 + lane]);
        }
    } else {  // K == 32: two edges per step, halves of the wave
        int half = lane >> 5;
        int dim = lane & 31;
        int e = 0;
        for (; e + 2 <= d; e += 2) {
            int s0 = __shfl(id, e, 64);
            int s1 = __shfl(id, e + 1, 64);
            int s = half ? s1 : s0;
            acc += __half2float(uin[s * 32 + dim]);
        }
        if (e < d) {  // wave-uniform branch (d uniform)
            int s = __shfl(id, e, 64);
            if (half == 0) acc += __half2float(uin[s * 32 + dim]);
        }
        acc += __shfl_xor(acc, 32, 64);  // both halves hold full per-dim sum
    }
    float m = acc / fmaxf((float)d_true, 1.0f);

    // linear in tangent space
    float h = bs[lane];
    #pragma unroll
    for (int k = 0; k < K; ++k)
        h = fmaf(__shfl(m, k, 64), Ws[k * 64 + lane], h);
    if (d_true == 0) h = 0.0f;  // segment_mean of empty segment is 0 (no bias)
    if (ACT) h = (h >= 0.0f) ? h : 0.2f * h;

    float t = exp_proj_log(h);

    if (POOL) {
        int g = min(max(batch[node], 0), N_GRAPHS - 1);
        atomicAdd(&pooled[g * 64 + lane], t);
        if (lane == 0) atomicAdd(&cntg[g], 1.0f);
    } else {
        uout[node * 64 + lane] = __float2half(t);
    }
}

// final head: mean -> exp/proj/log -> @Wl + bl -> expmap0 -> proj
__global__ void head_kernel(const float* __restrict__ pooled, const float* __restrict__ cntg,
                            const float* __restrict__ Wl, const float* __restrict__ bl,
                            float* __restrict__ out) {
    int g = blockIdx.x;
    int lane = threadIdx.x;
    float m = pooled[g * 64 + lane] / fmaxf(cntg[g], 1.0f);
    float z = exp_proj_log(m);
    float acc = 0.0f;
    #pragma unroll
    for (int k = 0; k < 64; ++k) {
        float zk = __shfl(z, k, 64);
        if (lane < D_OUT) acc = fmaf(zk, Wl[k * D_OUT + lane], acc);
    }
    float o = (lane < D_OUT) ? (acc + bl[lane]) : 0.0f;
    float n = fmaxf(sqrtf(wave_reduce_sum(o * o)), EPS);
    float v = tanhf(n) * o / n;
    float nv = fmaxf(sqrtf(wave_reduce_sum(v * v)), EPS);
    if (nv > MAX_NORM) v = v * (MAX_NORM / nv);
    if (lane < D_OUT) out[g * D_OUT + lane] = v;
}

// ---------------- launch ----------------

extern "C" void kernel_launch(void* const* d_in, const int* in_sizes, int n_in,
                              void* d_out, int out_size, void* d_ws, size_t ws_size,
                              hipStream_t stream) {
    const float* x   = (const float*)d_in[0];
    const int* edge  = (const int*)d_in[1];   // [2, E]
    const int* batch = (const int*)d_in[2];
    const float* W1  = (const float*)d_in[3];
    const float* b1  = (const float*)d_in[4];
    const float* W2  = (const float*)d_in[5];
    const float* b2  = (const float*)d_in[6];
    const float* W3  = (const float*)d_in[7];
    const float* b3  = (const float*)d_in[8];
    const float* Wl  = (const float*)d_in[9];
    const float* bl  = (const float*)d_in[10];
    float* out = (float*)d_out;

    const int N = N_NODES, E = N_EDGES, G = N_GRAPHS;
    const int* src = edge;
    const int* dst = edge + E;

    // workspace layout: [deg:int N][pooled:f G*64][cntg:f G][ell:u16 N*64]
    //                   [u0h:h N*32][u1h:h N*64][u2h:h N*64]
    char* ws = (char*)d_ws;
    int*    deg    = (int*)ws;
    float*  pooled = (float*)(deg + N);
    float*  cntg   = pooled + (size_t)G * 64;
    ushort* ell    = (ushort*)(cntg + G);
    __half* u0h    = (__half*)(ell + (size_t)N * ELL_CAP);
    __half* u1h    = u0h + (size_t)N * 32;
    __half* u2h    = u1h + (size_t)N * 64;

    size_t zero_bytes = ((size_t)N + (size_t)G * 64 + G) * 4;
    hipMemsetAsync(d_ws, 0, zero_bytes, stream);

    int blocksE   = (E + 255) / 256;
    int blocksN64 = (N * 64 + 255) / 256;   // one wave per node, 4 per block

    ell_fill_kernel<<<blocksE, 256, 0, stream>>>(src, dst, deg, ell, E);
    tangent0_kernel<<<blocksN64, 256, 0, stream>>>(x, u0h, N);

    // layer 1: gather u0 (K=32) -> @W1+b1 -> lrelu -> epl -> u1h
    layer_kernel<32, 1, 0><<<blocksN64, 256, 0, stream>>>(
        u0h, W1, b1, deg, ell, u1h, nullptr, nullptr, nullptr);
    // layer 2: gather u1 (K=64) -> @W2+b2 -> lrelu -> epl -> u2h
    layer_kernel<64, 1, 0><<<blocksN64, 256, 0, stream>>>(
        u1h, W2, b2, deg, ell, u2h, nullptr, nullptr, nullptr);
    // layer 3: gather u2 (K=64) -> @W3+b3 -> epl -> atomic pool
    layer_kernel<64, 0, 1><<<blocksN64, 256, 0, stream>>>(
        u2h, W3, b3, deg, ell, nullptr, batch, pooled, cntg);

    head_kernel<<<G, 64, 0, stream>>>(pooled, cntg, Wl, bl, out);
}

// Round 5
// 595.010 us; speedup vs baseline: 1.1565x; 1.1565x over previous
//
#include <hip/hip_runtime.h>
#include <hip/hip_fp16.h>
#include <math.h>

#define N_NODES 50000
#define N_EDGES 1200000
#define N_GRAPHS 128
#define D_IN 32
#define D_H 64
#define D_OUT 10
#define ELL_CAP 64

#define EPS 1e-7f
#define MAX_NORM (1.0f - 1e-5f)

typedef _Float16 half8 __attribute__((ext_vector_type(8)));
typedef float float4v __attribute__((ext_vector_type(4)));

// ---------------- wave helpers ----------------

__device__ __forceinline__ float wave_reduce_sum(float v) {
    #pragma unroll
    for (int off = 32; off > 0; off >>= 1)
        v += __shfl_xor(v, off, 64);
    return v;
}

// sum within each 32-lane half (both halves hold identical data afterwards
// when inputs are half-duplicated)
__device__ __forceinline__ float reduce32(float v) {
    #pragma unroll
    for (int off = 16; off > 0; off >>= 1)
        v += __shfl_xor(v, off, 64);
    return v;
}

// logmap0(proj(expmap0(u))) on a 64-lane-distributed vector (used by
// tangent0/head). Replicates the reference's exact op sequence.
__device__ __forceinline__ float exp_proj_log(float m) {
    float n = fmaxf(sqrtf(wave_reduce_sum(m * m)), EPS);
    float v = tanhf(n) * m / n;
    float nv = fmaxf(sqrtf(wave_reduce_sum(v * v)), EPS);
    if (nv > MAX_NORM) v = v * (MAX_NORM / nv);
    float nl = sqrtf(wave_reduce_sum(v * v));
    nl = fminf(fmaxf(nl, EPS), MAX_NORM);
    return atanhf(nl) * v / nl;
}

// ---------------- kernels ----------------

// Build ELL adjacency (ushort src ids): append src[e] to dst[e]'s row.
__global__ void ell_fill_kernel(const int* __restrict__ src, const int* __restrict__ dst,
                                int* __restrict__ deg, ushort* __restrict__ ell, int E) {
    int e = blockIdx.x * 256 + threadIdx.x;
    if (e >= E) return;
    int s = src[e];
    int d = dst[e];
    s = min(max(s, 0), N_NODES - 1);
    d = min(max(d, 0), N_NODES - 1);
    int pos = atomicAdd(&deg[d], 1);
    if (pos < ELL_CAP) ell[d * ELL_CAP + pos] = (ushort)s;
}

// u0 = fp16(logmap0(proj(expmap0(x)))), x: [N, 32]. One wave per node.
__global__ void tangent0_kernel(const float* __restrict__ x, __half* __restrict__ u0, int n) {
    int gid = blockIdx.x * 256 + threadIdx.x;
    int node = gid >> 6;
    int lane = gid & 63;
    if (node >= n) return;
    float m = (lane < D_IN) ? x[node * D_IN + lane] : 0.0f;
    float t = exp_proj_log(m);
    if (lane < D_IN) u0[node * D_IN + lane] = __float2half(t);
}

// Repack W (f32 [K,64]) into B-fragment order for mfma_f32_16x16x32_f16:
// Whf[((jb*NF + f)*64 + lane)*8 + j] = W[f*32 + (lane>>4)*8 + j][jb*16 + (lane&15)]
template <int K>
__global__ void repack_kernel(const float* __restrict__ W, __half* __restrict__ Whf) {
    const int NF = K / 32;
    int idx = blockIdx.x * 256 + threadIdx.x;
    if (idx >= 4 * NF * 64 * 8) return;
    int j = idx & 7;
    int lane = (idx >> 3) & 63;
    int f = (idx >> 9) % NF;
    int jb = (idx >> 9) / NF;
    int k = f * 32 + ((lane >> 4) * 8) + j;
    int n = jb * 16 + (lane & 15);
    Whf[idx] = __float2half(W[k * 64 + n]);
}

// t[N,64] fp16 = u[N,K] fp16 @ W + b via MFMA. One wave = 16 nodes x 16 cols.
// A-frag: A[m=lane&15][k=(lane>>4)*8+j] (m120-verified layout), loaded as
// contiguous half8 straight from the row-major fp16 table.
template <int K>
__global__ void gemm_kernel(const __half* __restrict__ u, const __half* __restrict__ Whf,
                            const float* __restrict__ b, __half* __restrict__ t) {
    const int NF = K / 32;
    int gw = blockIdx.x * 4 + (threadIdx.x >> 6);
    int lane = threadIdx.x & 63;
    int jb = gw & 3;
    int tile = gw >> 2;
    int node0 = tile * 16;
    if (node0 >= N_NODES) return;
    int m = lane & 15, quad = lane >> 4;

    float4v acc = {0.f, 0.f, 0.f, 0.f};
    const half8* bfr = (const half8*)Whf + (size_t)(jb * NF) * 64 + lane;
    #pragma unroll
    for (int f = 0; f < NF; ++f) {
        half8 a = *(const half8*)(u + (size_t)(node0 + m) * K + f * 32 + quad * 8);
        half8 bb = bfr[f * 64];
        acc = __builtin_amdgcn_mfma_f32_16x16x32_f16(a, bb, acc, 0, 0, 0);
    }
    int j = jb * 16 + m;
    float bias = b[j];
    #pragma unroll
    for (int r = 0; r < 4; ++r) {
        int node = node0 + quad * 4 + r;   // C/D: col=lane&15, row=quad*4+reg
        t[node * 64 + j] = __float2half(acc[r] + bias);
    }
}

// Gather-mean over ELL (half2-packed: half-wave per edge, lane owns dims
// 2*d2, 2*d2+1) -> act -> expmap0 -> proj -> logmap0 -> fp16 store / pool.
// One wave per node. No dot product here (it lives in gemm_kernel).
template <int ACT, int POOL>
__global__ void agg_kernel(const __half* __restrict__ t, const int* __restrict__ deg,
                           const ushort* __restrict__ ell, __half* __restrict__ uout,
                           const int* __restrict__ batch, float* __restrict__ pooled,
                           float* __restrict__ cntg) {
    int node = blockIdx.x * 4 + (threadIdx.x >> 6);
    int lane = threadIdx.x & 63;
    if (node >= N_NODES) return;
    int half_ = lane >> 5, d2 = lane & 31;
    int dt = deg[node];
    int d = min(dt, ELL_CAP);
    int id = (lane < d) ? (int)ell[node * ELL_CAP + lane] : 0;
    const __half2* t2 = (const __half2*)t;

    float ax = 0.f, ay = 0.f;
    int e = 0;
    for (; e + 4 <= d; e += 4) {   // 4 edges per iter: 2 bpermutes, 2 loads
        int sA = __shfl(id, e + half_, 64);
        int sB = __shfl(id, e + 2 + half_, 64);
        float2 fA = __half22float2(t2[sA * 32 + d2]);
        float2 fB = __half22float2(t2[sB * 32 + d2]);
        ax += fA.x + fB.x;
        ay += fA.y + fB.y;
    }
    if (e + 2 <= d) {
        int sA = __shfl(id, e + half_, 64);
        float2 fA = __half22float2(t2[sA * 32 + d2]);
        ax += fA.x; ay += fA.y;
        e += 2;
    }
    if (e < d) {                   // odd leftover: only half 0 accumulates
        int sA = __shfl(id, e, 64);
        if (half_ == 0) {
            float2 fA = __half22float2(t2[sA * 32 + d2]);
            ax += fA.x; ay += fA.y;
        }
    }
    ax += __shfl_xor(ax, 32, 64);  // combine halves; both now identical
    ay += __shfl_xor(ay, 32, 64);

    float inv = 1.0f / fmaxf((float)dt, 1.0f);
    float mx = ax * inv, my = ay * inv;
    if (ACT) {
        mx = (mx >= 0.f) ? mx : 0.2f * mx;
        my = (my >= 0.f) ? my : 0.2f * my;
    }
    // expmap0 -> proj -> logmap0 on the packed pair (reductions over 32 lanes)
    float n = fmaxf(sqrtf(reduce32(mx * mx + my * my)), EPS);
    float s = tanhf(n) / n;
    float vx = s * mx, vy = s * my;
    float nv = fmaxf(sqrtf(reduce32(vx * vx + vy * vy)), EPS);
    if (nv > MAX_NORM) { float sc = MAX_NORM / nv; vx *= sc; vy *= sc; }
    float nl = sqrtf(reduce32(vx * vx + vy * vy));
    nl = fminf(fmaxf(nl, EPS), MAX_NORM);
    float sl = atanhf(nl) / nl;
    float rx = sl * vx, ry = sl * vy;

    if (POOL) {
        int g = min(max(batch[node], 0), N_GRAPHS - 1);
        if (half_ == 0) {
            atomicAdd(&pooled[g * 64 + 2 * d2], rx);
            atomicAdd(&pooled[g * 64 + 2 * d2 + 1], ry);
        }
        if (lane == 0) atomicAdd(&cntg[g], 1.0f);
    } else {
        if (half_ == 0)
            ((__half2*)uout)[node * 32 + d2] = __floats2half2_rn(rx, ry);
    }
}

// final head: mean -> exp/proj/log -> @Wl + bl -> expmap0 -> proj
__global__ void head_kernel(const float* __restrict__ pooled, const float* __restrict__ cntg,
                            const float* __restrict__ Wl, const float* __restrict__ bl,
                            float* __restrict__ out) {
    int g = blockIdx.x;
    int lane = threadIdx.x;
    float m = pooled[g * 64 + lane] / fmaxf(cntg[g], 1.0f);
    float z = exp_proj_log(m);
    float acc = 0.0f;
    #pragma unroll
    for (int k = 0; k < 64; ++k) {
        float zk = __shfl(z, k, 64);
        if (lane < D_OUT) acc = fmaf(zk, Wl[k * D_OUT + lane], acc);
    }
    float o = (lane < D_OUT) ? (acc + bl[lane]) : 0.0f;
    float n = fmaxf(sqrtf(wave_reduce_sum(o * o)), EPS);
    float v = tanhf(n) * o / n;
    float nv = fmaxf(sqrtf(wave_reduce_sum(v * v)), EPS);
    if (nv > MAX_NORM) v = v * (MAX_NORM / nv);
    if (lane < D_OUT) out[g * D_OUT + lane] = v;
}

// ---------------- launch ----------------

extern "C" void kernel_launch(void* const* d_in, const int* in_sizes, int n_in,
                              void* d_out, int out_size, void* d_ws, size_t ws_size,
                              hipStream_t stream) {
    const float* x   = (const float*)d_in[0];
    const int* edge  = (const int*)d_in[1];   // [2, E]
    const int* batch = (const int*)d_in[2];
    const float* W1  = (const float*)d_in[3];
    const float* b1  = (const float*)d_in[4];
    const float* W2  = (const float*)d_in[5];
    const float* b2  = (const float*)d_in[6];
    const float* W3  = (const float*)d_in[7];
    const float* b3  = (const float*)d_in[8];
    const float* Wl  = (const float*)d_in[9];
    const float* bl  = (const float*)d_in[10];
    float* out = (float*)d_out;

    const int N = N_NODES, E = N_EDGES, G = N_GRAPHS;
    const int* src = edge;
    const int* dst = edge + E;

    // ws layout: [deg:int N][pooled:f G*64][cntg:f G][ell:u16 N*64]
    //            [u0h:h N*32][u1h:h N*64][u2h:h N*64][th:h N*64][Wh1][Wh2][Wh3]
    char* ws = (char*)d_ws;
    int*    deg    = (int*)ws;
    float*  pooled = (float*)(deg + N);
    float*  cntg   = pooled + (size_t)G * 64;
    ushort* ell    = (ushort*)(cntg + G);
    __half* u0h    = (__half*)(ell + (size_t)N * ELL_CAP);
    __half* u1h    = u0h + (size_t)N * 32;
    __half* u2h    = u1h + (size_t)N * 64;
    __half* th     = u2h + (size_t)N * 64;
    __half* Wh1    = th + (size_t)N * 64;     // 2048
    __half* Wh2    = Wh1 + 2048;              // 4096
    __half* Wh3    = Wh2 + 4096;              // 4096

    size_t zero_bytes = ((size_t)N + (size_t)G * 64 + G) * 4;
    hipMemsetAsync(d_ws, 0, zero_bytes, stream);

    int blocksE   = (E + 255) / 256;
    int blocksN64 = (N * 64 + 255) / 256;   // one wave per node, 4 per block
    int blocksG   = 3125;                   // 50000/16 tiles * 4 waves / 4 per block

    repack_kernel<32><<<8,  256, 0, stream>>>(W1, Wh1);
    repack_kernel<64><<<16, 256, 0, stream>>>(W2, Wh2);
    repack_kernel<64><<<16, 256, 0, stream>>>(W3, Wh3);
    ell_fill_kernel<<<blocksE, 256, 0, stream>>>(src, dst, deg, ell, E);
    tangent0_kernel<<<blocksN64, 256, 0, stream>>>(x, u0h, N);

    // layer 1: t = u0@W1+b1 (MFMA) ; gather-mean -> lrelu -> epl -> u1h
    gemm_kernel<32><<<blocksG, 256, 0, stream>>>(u0h, Wh1, b1, th);
    agg_kernel<1, 0><<<blocksN64, 256, 0, stream>>>(th, deg, ell, u1h, nullptr, nullptr, nullptr);
    // layer 2
    gemm_kernel<64><<<blocksG, 256, 0, stream>>>(u1h, Wh2, b2, th);
    agg_kernel<1, 0><<<blocksN64, 256, 0, stream>>>(th, deg, ell, u2h, nullptr, nullptr, nullptr);
    // layer 3 (no act) + fused pooling
    gemm_kernel<64><<<blocksG, 256, 0, stream>>>(u2h, Wh3, b3, th);
    agg_kernel<0, 1><<<blocksN64, 256, 0, stream>>>(th, deg, ell, nullptr, batch, pooled, cntg);

    head_kernel<<<G, 64, 0, stream>>>(pooled, cntg, Wl, bl, out);
}